// Round 1
// baseline (288.643 us; speedup 1.0000x reference)
//
#include <hip/hip_runtime.h>
#include <stdint.h>

#define N_REP 8
#define BATCH 32
#define NIN   128
#define NOUT  128
#define EDIM  1024
#define MDIM  130
#define ETILE 128

typedef __attribute__((ext_vector_type(8))) short short8;
typedef __attribute__((ext_vector_type(4))) float f32x4;

__device__ __forceinline__ unsigned short f2bf(float f) {
    union { float f; uint32_t u; } v;
    v.f = f;
    uint32_t u = v.u;
    uint32_t r = u + 0x7fffu + ((u >> 16) & 1u);   // RNE
    return (unsigned short)(r >> 16);
}

// Per (n,o): clamp/prune theta, apply multiplicative noise, abs-normalize.
// Emits S[n][o][m] (bf16, K-minor so MFMA A-op frags are contiguous) and bias[n][o].
__global__ void prep_kernel(const float* __restrict__ theta,
                            const float* __restrict__ noise,
                            unsigned short* __restrict__ Sg,
                            float* __restrict__ biasg) {
    const int n = blockIdx.x;
    const int o = threadIdx.x;                       // 0..127
    const float* nptr = noise + (size_t)n * MDIM * NOUT + o;
    float sum = 0.f;
    for (int m = 0; m < MDIM; ++m) {
        float t = theta[m * NOUT + o];
        t = fminf(fmaxf(t, -1.f), 1.f);
        if (fabsf(t) < 0.01f) t = 0.f;
        float tn = t * fmaf(nptr[m * NOUT], 0.2f, 0.9f);
        sum += fabsf(tn);
    }
    const float inv = 1.f / (sum + 1e-10f);
    float bias = 0.f;
    unsigned short* srow = Sg + ((size_t)n * NOUT + o) * NIN;
    for (int m = 0; m < MDIM; ++m) {
        float t = theta[m * NOUT + o];
        t = fminf(fmaxf(t, -1.f), 1.f);
        if (fabsf(t) < 0.01f) t = 0.f;
        float tn = t * fmaf(nptr[m * NOUT], 0.2f, 0.9f);
        float w = fabsf(tn) * inv;
        if (m < NIN) {
            srow[m] = f2bf(tn >= 0.f ? w : -w);      // W * sign
            if (tn < 0.f) bias += w;                 // Wneg contribution
        } else if (m == NIN) {
            if (tn >= 0.f) bias += w;                // Wpos of ones-column
        }                                            // m==129 (zeros col): nothing
    }
    biasg[n * NOUT + o] = bias;
}

// D[o][e] = sum_m S[n][m][o] * a[n][b][m][e]  (bf16 MFMA), + bias, printed tanh.
// LDS: a-tile 128x128 fp32 = exactly 64 KiB, XOR-swizzled so strided K-reads are
// 2-way bank aliasing (free per m136).
__global__ __launch_bounds__(256, 2)
void gemm_kernel(const float* __restrict__ a,
                 const unsigned short* __restrict__ Sg,
                 const float* __restrict__ biasg,
                 const float* __restrict__ eta,
                 float* __restrict__ out) {
    __shared__ float Alds[NIN * ETILE];              // 64 KiB
    const int bid = blockIdx.x;
    const int et  = bid & 7;
    const int nb  = bid >> 3;                        // n*B + b, 0..255
    const int n   = nb >> 5;
    const int tid = threadIdx.x;

    // ---- stage A tile (128 m x 128 e) fp32 -> LDS, swizzled ----
    {
        const float* abase = a + (size_t)nb * (NIN * EDIM) + et * ETILE;
        const int e4 = (tid & 31) << 2;              // 0,4,...,124
        const int m0 = tid >> 5;                     // 0..7
#pragma unroll
        for (int it = 0; it < 16; ++it) {
            const int m = m0 + (it << 3);
            const float4 v = *(const float4*)(abase + (size_t)m * EDIM + e4);
            const int x = ((m >> 3) & 1) << 4;       // swizzle bit4 by (m/8)&1
            *(float4*)&Alds[m * ETILE + (e4 ^ x)] = v;
        }
    }
    __syncthreads();

    const int lane = tid & 63;
    const int w = tid >> 6;                          // wave id, 2x2 over (o,e)
    const int r = lane & 15;
    const int q = lane >> 4;
    const int o_base = (w & 1) << 6;
    const int e_base = (w >> 1) << 6;

    // ---- preload S fragments straight from global (L1/L2-hot, 32 KiB per n) ----
    short8 sf[4][4];                                 // [fo][ks]
#pragma unroll
    for (int fo = 0; fo < 4; ++fo) {
        const int o = o_base + (fo << 4) + r;
        const unsigned short* sp = Sg + ((size_t)(n * NOUT + o) << 7) + (q << 3);
#pragma unroll
        for (int ks = 0; ks < 4; ++ks)
            sf[fo][ks] = *(const short8*)(sp + (ks << 5));
    }

    f32x4 acc[4][4];
#pragma unroll
    for (int fo = 0; fo < 4; ++fo)
#pragma unroll
        for (int fe = 0; fe < 4; ++fe)
            acc[fo][fe] = (f32x4){0.f, 0.f, 0.f, 0.f};

    const int xq = (q & 1) << 4;                     // swizzle term for frag reads
#pragma unroll
    for (int ks = 0; ks < 4; ++ks) {
        short8 af[4];
#pragma unroll
        for (int fe = 0; fe < 4; ++fe) {
            const int e = (e_base + (fe << 4) + r) ^ xq;
            const int mrow = (ks << 5) + (q << 3);
            short8 t;
#pragma unroll
            for (int j = 0; j < 8; ++j)
                t[j] = (short)f2bf(Alds[(mrow + j) * ETILE + e]);
            af[fe] = t;
        }
#pragma unroll
        for (int fo = 0; fo < 4; ++fo)
#pragma unroll
            for (int fe = 0; fe < 4; ++fe)
                acc[fo][fe] = __builtin_amdgcn_mfma_f32_16x16x32_bf16(
                    sf[fo][ks], af[fe], acc[fo][fe], 0, 0, 0);
    }

    // ---- epilogue: bias + printed tanh, store out[n][b][o][e] ----
    const float e0 = eta[0], e1 = eta[1], e2 = eta[2], e3 = eta[3];
    float* obase = out + (size_t)nb * (NOUT * EDIM) + et * ETILE;
#pragma unroll
    for (int fo = 0; fo < 4; ++fo) {
#pragma unroll
        for (int i = 0; i < 4; ++i) {
            const int o = o_base + (fo << 4) + (q << 2) + i;   // C/D: row = q*4+reg
            const float bias = biasg[n * NOUT + o];
            float* orow = obase + (size_t)o * EDIM;
#pragma unroll
            for (int fe = 0; fe < 4; ++fe) {
                const float z = acc[fo][fe][i] + bias;
                const float y = (z - e2) * e3;
                const float ex = __expf(2.f * y);              // exp(2y)
                const float th = 1.f - 2.f * __builtin_amdgcn_rcpf(ex + 1.f);
                orow[e_base + (fe << 4) + r] = fmaf(e1, th, e0); // C/D: col = r
            }
        }
    }
}

extern "C" void kernel_launch(void* const* d_in, const int* in_sizes, int n_in,
                              void* d_out, int out_size, void* d_ws, size_t ws_size,
                              hipStream_t stream) {
    const float* a     = (const float*)d_in[0];
    const float* theta = (const float*)d_in[1];
    const float* noise = (const float*)d_in[2];
    const float* eta   = (const float*)d_in[3];
    float* out = (float*)d_out;

    unsigned short* Sg = (unsigned short*)d_ws;      // 8*128*128 bf16 = 256 KiB
    float* biasg = (float*)((char*)d_ws + (size_t)N_REP * NOUT * NIN * sizeof(unsigned short));

    prep_kernel<<<N_REP, NOUT, 0, stream>>>(theta, noise, Sg, biasg);
    gemm_kernel<<<N_REP * BATCH * (EDIM / ETILE), 256, 0, stream>>>(a, Sg, biasg, eta, out);
}

// Round 2
// 254.569 us; speedup vs baseline: 1.1339x; 1.1339x over previous
//
#include <hip/hip_runtime.h>
#include <hip/hip_bf16.h>
#include <stdint.h>

#define N_REP 8
#define BATCH 32
#define NIN   128
#define NOUT  128
#define EDIM  1024
#define MDIM  130
#define ETILE 128
#define SE    130   // LDS row stride in dwords (mp rows); 130 => frag reads 2-way (free)

typedef __attribute__((ext_vector_type(8))) short short8;
typedef __attribute__((ext_vector_type(4))) float f32x4;

__device__ __forceinline__ unsigned short f2bf(float f) {
    union { float f; uint32_t u; } v;
    v.f = f;
    uint32_t u = v.u;
    uint32_t r = u + 0x7fffu + ((u >> 16) & 1u);   // RNE
    return (unsigned short)(r >> 16);
}

__device__ __forceinline__ uint32_t pk2bf(float lo, float hi) {
    __hip_bfloat162 h = __float22bfloat162_rn(make_float2(lo, hi)); // .x -> low16
    uint32_t d;
    __builtin_memcpy(&d, &h, 4);
    return d;
}

// One wave per (n,o). m parallel across lanes: m = lane, lane+64, (lane<2: 128+lane).
// Emits S[n][o][m] = W*sign (bf16, K-minor) and bias[n][o] = sum Wneg(m<128) + Wpos(m=128).
__global__ __launch_bounds__(64)
void prep_kernel(const float* __restrict__ theta,
                 const float* __restrict__ noise,
                 unsigned short* __restrict__ Sg,
                 float* __restrict__ biasg) {
    const int n = blockIdx.x >> 7;
    const int o = blockIdx.x & 127;
    const int lane = threadIdx.x;

    const float* nb = noise + (size_t)n * MDIM * NOUT + o;
    auto tn_at = [&](int m) -> float {
        float t = theta[m * NOUT + o];
        t = fminf(fmaxf(t, -1.f), 1.f);
        if (fabsf(t) < 0.01f) t = 0.f;
        return t * fmaf(nb[m * NOUT], 0.2f, 0.9f);
    };

    const float t0 = tn_at(lane);
    const float t1 = tn_at(lane + 64);
    const float t2 = (lane < 2) ? tn_at(128 + lane) : 0.f;

    float s = fabsf(t0) + fabsf(t1) + fabsf(t2);
#pragma unroll
    for (int d = 1; d < 64; d <<= 1) s += __shfl_xor(s, d, 64);
    const float inv = 1.f / (s + 1e-10f);

    const float w0 = fabsf(t0) * inv, w1 = fabsf(t1) * inv;
    unsigned short* srow = Sg + ((size_t)n * NOUT + o) * NIN;
    srow[lane]      = f2bf(t0 >= 0.f ? w0 : -w0);
    srow[lane + 64] = f2bf(t1 >= 0.f ? w1 : -w1);

    float b = (t0 < 0.f ? w0 : 0.f) + (t1 < 0.f ? w1 : 0.f);
    if (lane == 0 && t2 >= 0.f) b += fabsf(t2) * inv;   // ones-column positive part
#pragma unroll
    for (int d = 1; d < 64; d <<= 1) b += __shfl_xor(b, d, 64);
    if (lane == 0) biasg[n * NOUT + o] = b;
}

// D[o][e] = sum_m S[n][o][m] * a[n][b][m][e] via bf16 MFMA; + bias, printed tanh.
// LDS a-tile: bf16 packed m-pairs, Alds[mp*SE + e] = (bf16(2mp,e) | bf16(2mp+1,e)<<16).
// 32.5 KiB => 4 blocks/CU. Frag = 4 x ds_read_b32, no repacking.
__global__ __launch_bounds__(256, 4)
void gemm_kernel(const float* __restrict__ a,
                 const unsigned short* __restrict__ Sg,
                 const float* __restrict__ biasg,
                 const float* __restrict__ eta,
                 float* __restrict__ out) {
    __shared__ uint32_t Alds[64 * SE];               // 33280 B
    const int bid = blockIdx.x;
    const int et  = bid & 7;
    const int nb  = bid >> 3;                        // n*B + b
    const int n   = nb >> 5;
    const int tid = threadIdx.x;

    // ---- stage A tile: fp32 [m][e] -> bf16 m-pair-packed [mp][e] ----
    {
        const float* abase = a + (size_t)nb * (NIN * EDIM) + et * ETILE;
        const int e4  = (tid & 31) << 2;
        const int mp0 = tid >> 5;                    // 0..7
#pragma unroll
        for (int it = 0; it < 8; ++it) {
            const int mp = mp0 + (it << 3);
            const float4 va = *(const float4*)(abase + (size_t)(2 * mp) * EDIM + e4);
            const float4 vb = *(const float4*)(abase + (size_t)(2 * mp + 1) * EDIM + e4);
            uint2 d0, d1;
            d0.x = pk2bf(va.x, vb.x);
            d0.y = pk2bf(va.y, vb.y);
            d1.x = pk2bf(va.z, vb.z);
            d1.y = pk2bf(va.w, vb.w);
            *(uint2*)&Alds[mp * SE + e4]     = d0;
            *(uint2*)&Alds[mp * SE + e4 + 2] = d1;
        }
    }
    __syncthreads();

    const int lane = tid & 63;
    const int w = tid >> 6;                          // 2x2 waves over (o,e)
    const int r = lane & 15;
    const int q = lane >> 4;
    const int o_base = (w & 1) << 6;
    const int e_base = (w >> 1) << 6;

    f32x4 acc[4][4];
#pragma unroll
    for (int fo = 0; fo < 4; ++fo)
#pragma unroll
        for (int fe = 0; fe < 4; ++fe)
            acc[fo][fe] = (f32x4){0.f, 0.f, 0.f, 0.f};

#pragma unroll
    for (int ks = 0; ks < 4; ++ks) {
        // S fragments (A-operand): contiguous 16 B from global (L2-hot, 32 KiB/n)
        short8 sf[4];
#pragma unroll
        for (int fo = 0; fo < 4; ++fo) {
            const int o = o_base + (fo << 4) + r;
            sf[fo] = *(const short8*)(Sg + ((size_t)(n * NOUT + o) << 7) + (ks << 5) + (q << 3));
        }
        // a fragments (B-operand): 4 dwords each, dword = 2 consecutive-k bf16
        short8 af[4];
        const int mpb = (ks << 4) + (q << 2);
#pragma unroll
        for (int fe = 0; fe < 4; ++fe) {
            const int e = e_base + (fe << 4) + r;
            uint32_t d[4];
#pragma unroll
            for (int jj = 0; jj < 4; ++jj)
                d[jj] = Alds[(mpb + jj) * SE + e];
            __builtin_memcpy(&af[fe], d, 16);
        }
#pragma unroll
        for (int fo = 0; fo < 4; ++fo)
#pragma unroll
            for (int fe = 0; fe < 4; ++fe)
                acc[fo][fe] = __builtin_amdgcn_mfma_f32_16x16x32_bf16(
                    sf[fo], af[fe], acc[fo][fe], 0, 0, 0);
    }

    // ---- epilogue: bias + printed tanh, store out[n][b][o][e] ----
    const float e0 = eta[0], e1 = eta[1], e2 = eta[2], e3 = eta[3];
    float* obase = out + (size_t)nb * (NOUT * EDIM) + et * ETILE;
#pragma unroll
    for (int fo = 0; fo < 4; ++fo) {
        const int orow0 = o_base + (fo << 4) + (q << 2);       // C/D: row = q*4+i
        const float4 bias4 = *(const float4*)(biasg + n * NOUT + orow0);
        const float bv[4] = {bias4.x, bias4.y, bias4.z, bias4.w};
#pragma unroll
        for (int i = 0; i < 4; ++i) {
            float* orow = obase + (size_t)(orow0 + i) * EDIM;
#pragma unroll
            for (int fe = 0; fe < 4; ++fe) {
                const float z = acc[fo][fe][i] + bv[i];
                const float y = (z - e2) * e3;
                const float ex = __expf(2.f * y);
                const float th = 1.f - 2.f * __builtin_amdgcn_rcpf(ex + 1.f);
                orow[e_base + (fe << 4) + r] = fmaf(e1, th, e0);  // C/D: col = r
            }
        }
    }
}

extern "C" void kernel_launch(void* const* d_in, const int* in_sizes, int n_in,
                              void* d_out, int out_size, void* d_ws, size_t ws_size,
                              hipStream_t stream) {
    const float* a     = (const float*)d_in[0];
    const float* theta = (const float*)d_in[1];
    const float* noise = (const float*)d_in[2];
    const float* eta   = (const float*)d_in[3];
    float* out = (float*)d_out;

    unsigned short* Sg = (unsigned short*)d_ws;      // 8*128*128 bf16 = 256 KiB
    float* biasg = (float*)((char*)d_ws + (size_t)N_REP * NOUT * NIN * sizeof(unsigned short));

    prep_kernel<<<N_REP * NOUT, 64, 0, stream>>>(theta, noise, Sg, biasg);
    gemm_kernel<<<N_REP * BATCH * (EDIM / ETILE), 256, 0, stream>>>(a, Sg, biasg, eta, out);
}